// Round 1
// baseline (1347.968 us; speedup 1.0000x reference)
//
#include <hip/hip_runtime.h>

#define NB   2000   // N
#define HH   4      // heads
#define KK   20     // topk
#define BLT  128    // B*L
#define EPSF 1e-8f

// ---------------------------------------------------------------------------
// Kernel 1: per (head, row): scores = e1[h,n,:] . e2[h,:,m]; t = relu/temp;
// softmax; top-20 (value desc, index asc tiebreak = jax.lax.top_k semantics);
// renormalize selected adj by (sum_sel + eps). Emit sparse (idx, val).
// ---------------------------------------------------------------------------
__global__ __launch_bounds__(256) void k_scores_topk(
    const float* __restrict__ e1, const float* __restrict__ e2,
    const float* __restrict__ temperature,
    int* __restrict__ topk_idx, float* __restrict__ topk_val)
{
    const int n = blockIdx.x;
    const int h = blockIdx.y;
    const int t = threadIdx.x;

    __shared__ float e1s[64];
    __shared__ float adjs[NB];
    __shared__ float redf[8];
    __shared__ int   redi[8];
    __shared__ int   sel_i[KK];
    __shared__ float sel_v[KK];
    __shared__ float bcast[2];

    if (t < 64) e1s[t] = e1[(h * NB + n) * 64 + t];
    __syncthreads();

    const float temp = temperature[h];
    const float* __restrict__ e2h = e2 + (size_t)h * 64 * NB;

    // scores: thread t owns columns m = k*256 + t
    float acc[8];
#pragma unroll
    for (int k = 0; k < 8; k++) acc[k] = 0.f;
    for (int d = 0; d < 64; d++) {
        float ev = e1s[d];
        const float* __restrict__ row = e2h + d * NB;
#pragma unroll
        for (int k = 0; k < 8; k++) {
            int m = k * 256 + t;
            if (m < NB) acc[k] += ev * row[m];
        }
    }

    // t = relu(score)/temp ; row max (all values >= 0)
    float tv[8];
    float lmax = 0.f;
#pragma unroll
    for (int k = 0; k < 8; k++) {
        int m = k * 256 + t;
        float v = (m < NB) ? fmaxf(acc[k], 0.f) / temp : 0.f;
        tv[k] = v;
        if (m < NB) lmax = fmaxf(lmax, v);
    }
    for (int off = 32; off; off >>= 1) lmax = fmaxf(lmax, __shfl_xor(lmax, off, 64));
    if ((t & 63) == 0) redf[t >> 6] = lmax;
    __syncthreads();
    const float mx = fmaxf(fmaxf(redf[0], redf[1]), fmaxf(redf[2], redf[3]));
    __syncthreads();   // protect redf reuse below

    // p = exp(t - mx); Z = sum
    float pv[8];
    float lsum = 0.f;
#pragma unroll
    for (int k = 0; k < 8; k++) {
        int m = k * 256 + t;
        pv[k] = (m < NB) ? expf(tv[k] - mx) : 0.f;
        lsum += pv[k];
    }
    for (int off = 32; off; off >>= 1) lsum += __shfl_xor(lsum, off, 64);
    if ((t & 63) == 0) redf[t >> 6] = lsum;
    __syncthreads();
    const float Z = (redf[0] + redf[1]) + (redf[2] + redf[3]);

#pragma unroll
    for (int k = 0; k < 8; k++) {
        int m = k * 256 + t;
        if (m < NB) adjs[m] = pv[k] / Z;
    }
    __syncthreads();

    // 20 rounds of block argmax (lexicographic: value desc, index asc)
    float ssum = 0.f;  // thread 0 only
    for (int r = 0; r < KK; r++) {
        float bv = -1.f;
        int   bi = 0x7fffffff;
#pragma unroll
        for (int k = 0; k < 8; k++) {
            int m = k * 256 + t;
            if (m < NB) {
                float v = adjs[m];
                if (v > bv || (v == bv && m < bi)) { bv = v; bi = m; }
            }
        }
        for (int off = 32; off; off >>= 1) {
            float ov = __shfl_xor(bv, off, 64);
            int   oi = __shfl_xor(bi, off, 64);
            if (ov > bv || (ov == bv && oi < bi)) { bv = ov; bi = oi; }
        }
        if ((t & 63) == 0) { redf[t >> 6] = bv; redi[t >> 6] = bi; }
        __syncthreads();
        if (t == 0) {
            float v = redf[0]; int i = redi[0];
            for (int w = 1; w < 4; w++)
                if (redf[w] > v || (redf[w] == v && redi[w] < i)) { v = redf[w]; i = redi[w]; }
            sel_i[r] = i; sel_v[r] = v; ssum += v;
            adjs[i] = -1.f;   // mark consumed
        }
        __syncthreads();
    }
    if (t == 0) bcast[0] = ssum;
    __syncthreads();
    if (t < KK) {
        int o = (h * NB + n) * KK + t;
        topk_idx[o] = sel_i[t];
        topk_val[o] = sel_v[t] / (bcast[0] + EPSF);
    }
}

// ---------------------------------------------------------------------------
// Kernel 2: per row i: scatter 4 heads' topk into dense LDS rows; for each j:
// mean over heads; if >0 run edge MLP -> final_adj[i,j]; write dense row to
// d_out and scatter nonzeros into faT[j][i] (pre-zeroed).
// ---------------------------------------------------------------------------
__global__ __launch_bounds__(256) void k_final_adj(
    const int* __restrict__ topk_idx, const float* __restrict__ topk_val,
    const float* __restrict__ ew1, const float* __restrict__ eb1,
    const float* __restrict__ ew2, const float* __restrict__ eb2,
    float* __restrict__ fadj_out, float* __restrict__ faT)
{
    const int i = blockIdx.x;
    const int t = threadIdx.x;

    __shared__ float rows[HH][NB];
    __shared__ float w1[32];
    __shared__ float b1[8];
    __shared__ float w2[8];
    __shared__ float b2v;

    for (int k = t; k < HH * NB; k += 256) ((float*)rows)[k] = 0.f;
    if (t < 32) w1[t] = ew1[t];
    if (t < 8)  { b1[t] = eb1[t]; w2[t] = ew2[t]; }
    if (t == 0) b2v = eb2[0];
    __syncthreads();

    if (t < HH * KK) {
        int h = t / KK, r = t % KK;
        int o = (h * NB + i) * KK + r;
        rows[h][topk_idx[o]] = topk_val[o];
    }
    __syncthreads();

#pragma unroll
    for (int k = 0; k < 8; k++) {
        int j = k * 256 + t;
        if (j < NB) {
            float f0 = rows[0][j], f1 = rows[1][j], f2 = rows[2][j], f3 = rows[3][j];
            float mean = (f0 + f1 + f2 + f3) * 0.25f;
            float outv = 0.f;
            if (mean > 0.f) {
                float ewv = b2v;
#pragma unroll
                for (int c = 0; c < 8; c++) {
                    float hid = f0 * w1[c] + f1 * w1[8 + c] + f2 * w1[16 + c] + f3 * w1[24 + c] + b1[c];
                    hid = fmaxf(hid, 0.f);
                    ewv += hid * w2[c];
                }
                float sig = 1.f / (1.f + expf(-ewv));
                outv = sig * mean;
                faT[(size_t)j * NB + i] = outv;
            }
            fadj_out[(size_t)i * NB + j] = outv;
        }
    }
}

// ---------------------------------------------------------------------------
// Kernel 3: support S[j][bl*64+d] = sum_d0 x[b_,j,l,d0] * W[d0,d]
// (j-major layout so k_out's row gather is one contiguous 32KB read)
// ---------------------------------------------------------------------------
__global__ __launch_bounds__(256) void k_support(
    const float* __restrict__ x, const float* __restrict__ w,
    float* __restrict__ S)
{
    const int j = blockIdx.x;
    const int t = threadIdx.x;

    __shared__ float xs[BLT * 65];   // +1 pad: bank-conflict-free row reads
    __shared__ float ws[64 * 64];

    for (int k = t; k < 4096; k += 256) ws[k] = w[k];
    for (int idx = t; idx < 8192; idx += 256) {
        int b_ = idx >> 11, rem = idx & 2047;
        int bl = (b_ << 5) + (rem >> 6), dd = rem & 63;
        xs[bl * 65 + dd] = x[(size_t)b_ * 4096000 + (size_t)j * 2048 + rem];
    }
    __syncthreads();

    const int dq = t & 15;   // d-quad
    const int g  = t >> 4;   // bl-group of 8
    float acc[8][4];
#pragma unroll
    for (int r = 0; r < 8; r++)
#pragma unroll
        for (int c = 0; c < 4; c++) acc[r][c] = 0.f;

    for (int dd = 0; dd < 64; dd++) {
        float4 w4 = *(const float4*)&ws[dd * 64 + dq * 4];
#pragma unroll
        for (int r = 0; r < 8; r++) {
            float xv = xs[(g * 8 + r) * 65 + dd];
            acc[r][0] += xv * w4.x;
            acc[r][1] += xv * w4.y;
            acc[r][2] += xv * w4.z;
            acc[r][3] += xv * w4.w;
        }
    }

#pragma unroll
    for (int r = 0; r < 8; r++) {
        int bl = g * 8 + r;
        float4 v = make_float4(acc[r][0], acc[r][1], acc[r][2], acc[r][3]);
        *(float4*)&S[(size_t)j * 8192 + bl * 64 + dq * 4] = v;
    }
}

// ---------------------------------------------------------------------------
// Kernel 4: out[b_,i,l,d] = sum_j fa[j,i] * S[j, bl*64+d] + bias[d]
// Block per column i: compact nonzeros of faT row i in LDS, then gather-GEMM.
// ---------------------------------------------------------------------------
__global__ __launch_bounds__(256) void k_out(
    const float* __restrict__ faT, const float* __restrict__ S,
    const float* __restrict__ bias, float* __restrict__ out)
{
    const int i = blockIdx.x;
    const int t = threadIdx.x;

    __shared__ int   sj[NB];
    __shared__ float sv[NB];
    __shared__ int   scnt;

    if (t == 0) scnt = 0;
    __syncthreads();

#pragma unroll
    for (int k = 0; k < 8; k++) {
        int j = k * 256 + t;
        if (j < NB) {
            float v = faT[(size_t)i * NB + j];
            if (v != 0.f) {
                int p = atomicAdd(&scnt, 1);
                sj[p] = j; sv[p] = v;
            }
        }
    }
    __syncthreads();
    const int nnz = scnt;

    float acc[8][4];
#pragma unroll
    for (int kp = 0; kp < 8; kp++)
#pragma unroll
        for (int c = 0; c < 4; c++) acc[kp][c] = 0.f;

    for (int e = 0; e < nnz; e++) {
        int   j = sj[e];
        float v = sv[e];
        const float4* __restrict__ sr = (const float4*)&S[(size_t)j * 8192];
#pragma unroll
        for (int kp = 0; kp < 8; kp++) {
            float4 s4 = sr[kp * 256 + t];
            acc[kp][0] += v * s4.x;
            acc[kp][1] += v * s4.y;
            acc[kp][2] += v * s4.z;
            acc[kp][3] += v * s4.w;
        }
    }

    float4 b4 = *(const float4*)&bias[(t * 4) & 63];
#pragma unroll
    for (int kp = 0; kp < 8; kp++) {
        int q  = kp * 1024 + t * 4;       // bl*64 + d
        int b_ = q >> 11, rem = q & 2047; // b index, (l*64+d)
        float4 v = make_float4(acc[kp][0] + b4.x, acc[kp][1] + b4.y,
                               acc[kp][2] + b4.z, acc[kp][3] + b4.w);
        *(float4*)&out[(size_t)b_ * 4096000 + (size_t)i * 2048 + rem] = v;
    }
}

// ---------------------------------------------------------------------------
extern "C" void kernel_launch(void* const* d_in, const int* in_sizes, int n_in,
                              void* d_out, int out_size, void* d_ws, size_t ws_size,
                              hipStream_t stream)
{
    const float* x           = (const float*)d_in[0];
    const float* e1          = (const float*)d_in[1];
    const float* e2          = (const float*)d_in[2];
    const float* temperature = (const float*)d_in[3];
    const float* ew1         = (const float*)d_in[4];
    const float* eb1         = (const float*)d_in[5];
    const float* ew2         = (const float*)d_in[6];
    const float* eb2         = (const float*)d_in[7];
    const float* weight      = (const float*)d_in[8];
    const float* bias        = (const float*)d_in[9];

    float* out  = (float*)d_out;            // (B,N,L,DOUT) = 16,384,000 floats
    float* fadj = out + 16384000;           // (N,N)        =  4,000,000 floats

    float* S        = (float*)d_ws;         // 16,384,000 floats (j-major support)
    float* faT      = S + 16384000;         //  4,000,000 floats (fa transposed)
    int*   topk_idx = (int*)(faT + 4000000);      // 160,000 ints
    float* topk_val = (float*)(topk_idx + 160000);// 160,000 floats

    hipMemsetAsync(faT, 0, (size_t)NB * NB * sizeof(float), stream);

    k_scores_topk<<<dim3(NB, HH), 256, 0, stream>>>(e1, e2, temperature,
                                                    topk_idx, topk_val);
    k_support<<<NB, 256, 0, stream>>>(x, weight, S);
    k_final_adj<<<NB, 256, 0, stream>>>(topk_idx, topk_val, ew1, eb1, ew2, eb2,
                                        fadj, faT);
    k_out<<<NB, 256, 0, stream>>>(faT, S, bias, out);
}

// Round 2
// 792.256 us; speedup vs baseline: 1.7014x; 1.7014x over previous
//
#include <hip/hip_runtime.h>

#define NB   2000   // N
#define HH   4      // heads
#define KK   20     // topk
#define KP   2048   // padded K (j) dim for GEMM
#define EPSF 1e-8f

typedef unsigned short ushort;
using short8   = __attribute__((ext_vector_type(8))) short;
using floatx4  = __attribute__((ext_vector_type(4))) float;
using ushortx4 = __attribute__((ext_vector_type(4))) unsigned short;
using ushortx8 = __attribute__((ext_vector_type(8))) unsigned short;

__device__ inline ushort f2bf(float f) {
    unsigned u = __builtin_bit_cast(unsigned, f);
    u += 0x7fffu + ((u >> 16) & 1u);   // round-to-nearest-even
    return (ushort)(u >> 16);
}

// ---------------------------------------------------------------------------
// Kernel 1 (unchanged): per (head,row) scores -> softmax -> top-20 -> renorm.
// Stays fp32: top-k selection boundaries are the precision-critical part.
// ---------------------------------------------------------------------------
__global__ __launch_bounds__(256) void k_scores_topk(
    const float* __restrict__ e1, const float* __restrict__ e2,
    const float* __restrict__ temperature,
    int* __restrict__ topk_idx, float* __restrict__ topk_val)
{
    const int n = blockIdx.x;
    const int h = blockIdx.y;
    const int t = threadIdx.x;

    __shared__ float e1s[64];
    __shared__ float adjs[NB];
    __shared__ float redf[8];
    __shared__ int   redi[8];
    __shared__ int   sel_i[KK];
    __shared__ float sel_v[KK];
    __shared__ float bcast[2];

    if (t < 64) e1s[t] = e1[(h * NB + n) * 64 + t];
    __syncthreads();

    const float temp = temperature[h];
    const float* __restrict__ e2h = e2 + (size_t)h * 64 * NB;

    float acc[8];
#pragma unroll
    for (int k = 0; k < 8; k++) acc[k] = 0.f;
    for (int d = 0; d < 64; d++) {
        float ev = e1s[d];
        const float* __restrict__ row = e2h + d * NB;
#pragma unroll
        for (int k = 0; k < 8; k++) {
            int m = k * 256 + t;
            if (m < NB) acc[k] += ev * row[m];
        }
    }

    float tv[8];
    float lmax = 0.f;
#pragma unroll
    for (int k = 0; k < 8; k++) {
        int m = k * 256 + t;
        float v = (m < NB) ? fmaxf(acc[k], 0.f) / temp : 0.f;
        tv[k] = v;
        if (m < NB) lmax = fmaxf(lmax, v);
    }
    for (int off = 32; off; off >>= 1) lmax = fmaxf(lmax, __shfl_xor(lmax, off, 64));
    if ((t & 63) == 0) redf[t >> 6] = lmax;
    __syncthreads();
    const float mx = fmaxf(fmaxf(redf[0], redf[1]), fmaxf(redf[2], redf[3]));
    __syncthreads();

    float pv[8];
    float lsum = 0.f;
#pragma unroll
    for (int k = 0; k < 8; k++) {
        int m = k * 256 + t;
        pv[k] = (m < NB) ? expf(tv[k] - mx) : 0.f;
        lsum += pv[k];
    }
    for (int off = 32; off; off >>= 1) lsum += __shfl_xor(lsum, off, 64);
    if ((t & 63) == 0) redf[t >> 6] = lsum;
    __syncthreads();
    const float Z = (redf[0] + redf[1]) + (redf[2] + redf[3]);

#pragma unroll
    for (int k = 0; k < 8; k++) {
        int m = k * 256 + t;
        if (m < NB) adjs[m] = pv[k] / Z;
    }
    __syncthreads();

    float ssum = 0.f;
    for (int r = 0; r < KK; r++) {
        float bv = -1.f;
        int   bi = 0x7fffffff;
#pragma unroll
        for (int k = 0; k < 8; k++) {
            int m = k * 256 + t;
            if (m < NB) {
                float v = adjs[m];
                if (v > bv || (v == bv && m < bi)) { bv = v; bi = m; }
            }
        }
        for (int off = 32; off; off >>= 1) {
            float ov = __shfl_xor(bv, off, 64);
            int   oi = __shfl_xor(bi, off, 64);
            if (ov > bv || (ov == bv && oi < bi)) { bv = ov; bi = oi; }
        }
        if ((t & 63) == 0) { redf[t >> 6] = bv; redi[t >> 6] = bi; }
        __syncthreads();
        if (t == 0) {
            float v = redf[0]; int i = redi[0];
            for (int w = 1; w < 4; w++)
                if (redf[w] > v || (redf[w] == v && redi[w] < i)) { v = redf[w]; i = redi[w]; }
            sel_i[r] = i; sel_v[r] = v; ssum += v;
            adjs[i] = -1.f;
        }
        __syncthreads();
    }
    if (t == 0) bcast[0] = ssum;
    __syncthreads();
    if (t < KK) {
        int o = (h * NB + n) * KK + t;
        topk_idx[o] = sel_i[t];
        topk_val[o] = sel_v[t] / (bcast[0] + EPSF);
    }
}

// ---------------------------------------------------------------------------
// Kernel 2: final_adj row i; writes dense fp32 fadj (output) and scatters
// nonzeros into bf16 A-matrix: faT_b[m=i_out][k=j] = final_adj[j][i_out],
// i.e. faT_b[(j_loop)*KP + blockIdx] -- faT_b pre-zeroed (K padded to 2048).
// ---------------------------------------------------------------------------
__global__ __launch_bounds__(256) void k_final_adj(
    const int* __restrict__ topk_idx, const float* __restrict__ topk_val,
    const float* __restrict__ ew1, const float* __restrict__ eb1,
    const float* __restrict__ ew2, const float* __restrict__ eb2,
    float* __restrict__ fadj_out, ushort* __restrict__ faT_b)
{
    const int i = blockIdx.x;
    const int t = threadIdx.x;

    __shared__ float rows[HH][NB];
    __shared__ float w1[32];
    __shared__ float b1[8];
    __shared__ float w2[8];
    __shared__ float b2v;

    for (int k = t; k < HH * NB; k += 256) ((float*)rows)[k] = 0.f;
    if (t < 32) w1[t] = ew1[t];
    if (t < 8)  { b1[t] = eb1[t]; w2[t] = ew2[t]; }
    if (t == 0) b2v = eb2[0];
    __syncthreads();

    if (t < HH * KK) {
        int h = t / KK, r = t % KK;
        int o = (h * NB + i) * KK + r;
        rows[h][topk_idx[o]] = topk_val[o];
    }
    __syncthreads();

#pragma unroll
    for (int k = 0; k < 8; k++) {
        int j = k * 256 + t;
        if (j < NB) {
            float f0 = rows[0][j], f1 = rows[1][j], f2 = rows[2][j], f3 = rows[3][j];
            float mean = (f0 + f1 + f2 + f3) * 0.25f;
            float outv = 0.f;
            if (mean > 0.f) {
                float ewv = b2v;
#pragma unroll
                for (int c = 0; c < 8; c++) {
                    float hid = f0 * w1[c] + f1 * w1[8 + c] + f2 * w1[16 + c] + f3 * w1[24 + c] + b1[c];
                    hid = fmaxf(hid, 0.f);
                    ewv += hid * w2[c];
                }
                float sig = 1.f / (1.f + expf(-ewv));
                outv = sig * mean;
                faT_b[(size_t)j * KP + i] = f2bf(outv);  // A[m=i][k=j] scatter
            }
            fadj_out[(size_t)i * NB + j] = outv;
        }
    }
}

// ---------------------------------------------------------------------------
// Kernel 3: support S_b[j][bl*64+d] (bf16, j-major) = x[b,j,l,:] @ W
// ---------------------------------------------------------------------------
__global__ __launch_bounds__(256) void k_support(
    const float* __restrict__ x, const float* __restrict__ w,
    ushort* __restrict__ S_b)
{
    const int j = blockIdx.x;
    const int t = threadIdx.x;

    __shared__ float xs[128 * 65];
    __shared__ float ws[64 * 64];

    for (int k = t; k < 4096; k += 256) ws[k] = w[k];
    for (int idx = t; idx < 8192; idx += 256) {
        int b_ = idx >> 11, rem = idx & 2047;
        int bl = (b_ << 5) + (rem >> 6), dd = rem & 63;
        xs[bl * 65 + dd] = x[(size_t)b_ * 4096000 + (size_t)j * 2048 + rem];
    }
    __syncthreads();

    const int dq = t & 15;
    const int g  = t >> 4;
    float acc[8][4];
#pragma unroll
    for (int r = 0; r < 8; r++)
#pragma unroll
        for (int c = 0; c < 4; c++) acc[r][c] = 0.f;

    for (int dd = 0; dd < 64; dd++) {
        float4 w4 = *(const float4*)&ws[dd * 64 + dq * 4];
#pragma unroll
        for (int r = 0; r < 8; r++) {
            float xv = xs[(g * 8 + r) * 65 + dd];
            acc[r][0] += xv * w4.x;
            acc[r][1] += xv * w4.y;
            acc[r][2] += xv * w4.z;
            acc[r][3] += xv * w4.w;
        }
    }

#pragma unroll
    for (int r = 0; r < 8; r++) {
        int bl = g * 8 + r;
        ushortx4 v;
        v.x = f2bf(acc[r][0]); v.y = f2bf(acc[r][1]);
        v.z = f2bf(acc[r][2]); v.w = f2bf(acc[r][3]);
        *(ushortx4*)&S_b[(size_t)j * 8192 + bl * 64 + dq * 4] = v;
    }
}

// ---------------------------------------------------------------------------
// Kernel 4: transpose S_b[j][c] (2000x8192 bf16) -> ST[c][j] (8192xKP bf16),
// zero-padding j in [2000,2048). 64x64 tiles via LDS.
// ---------------------------------------------------------------------------
__global__ __launch_bounds__(256) void k_transpose(
    const ushort* __restrict__ S_b, ushort* __restrict__ ST)
{
    const int jt = blockIdx.x;   // 0..31  (j tiles of 64, covers 2048)
    const int ct = blockIdx.y;   // 0..127 (c tiles of 64)
    const int t  = threadIdx.x;

    __shared__ ushort tile[64 * 65];

#pragma unroll
    for (int p = 0; p < 4; p++) {
        int q = p * 256 + t;          // 64 rows x 16 segs of 4 ushorts
        int row = q >> 4, seg = q & 15;
        int j = jt * 64 + row;
        ushort v0 = 0, v1 = 0, v2 = 0, v3 = 0;
        if (j < NB) {
            const ushort* src = &S_b[(size_t)j * 8192 + ct * 64 + seg * 4];
            v0 = src[0]; v1 = src[1]; v2 = src[2]; v3 = src[3];
        }
        ushort* dst = &tile[row * 65 + seg * 4];
        dst[0] = v0; dst[1] = v1; dst[2] = v2; dst[3] = v3;
    }
    __syncthreads();

#pragma unroll
    for (int p = 0; p < 2; p++) {
        int q = p * 256 + t;          // 64 c-rows x 8 segs of 8 ushorts
        int rc = q >> 3, s = q & 7;
        ushortx8 o;
#pragma unroll
        for (int k = 0; k < 8; k++) o[k] = tile[(s * 8 + k) * 65 + rc];
        *(ushortx8*)&ST[(size_t)(ct * 64 + rc) * KP + jt * 64 + s * 8] = o;
    }
}

// ---------------------------------------------------------------------------
// Kernel 5: MFMA bf16 GEMM: out[i][c] = sum_j A[i][j] * B[c][j]
//   A = faT_b (2048 x KP), B = ST (8192 x KP), K = 2048 (zero-padded)
//   128x128 block tile, BK=64, 4 waves in 2x2, each 64x64 via 4x4 16x16 frags.
//   LDS rows padded 64->72 ushorts to break bank aliasing (m98 evidence).
// ---------------------------------------------------------------------------
#define BKU 72
__global__ __launch_bounds__(256) void k_gemm(
    const ushort* __restrict__ A, const ushort* __restrict__ B,
    const float* __restrict__ bias, float* __restrict__ out)
{
    __shared__ ushort As[128 * BKU];
    __shared__ ushort Bs[128 * BKU];

    const int t    = threadIdx.x;
    const int lane = t & 63, wave = t >> 6;
    const int wm   = wave & 1, wn = wave >> 1;
    const int i0   = blockIdx.x * 128;   // m tile (16 tiles, rows >=2000 guarded)
    const int c0   = blockIdx.y * 128;   // n tile (64 tiles)
    const int srow = t >> 3, sseg = t & 7;

    floatx4 acc[4][4];
#pragma unroll
    for (int r = 0; r < 4; r++)
#pragma unroll
        for (int c = 0; c < 4; c++) acc[r][c] = (floatx4)(0.f);

    for (int kb = 0; kb < 32; kb++) {
        __syncthreads();
#pragma unroll
        for (int p = 0; p < 4; p++) {
            int row = p * 32 + srow;
            uint4 av = *(const uint4*)&A[(size_t)(i0 + row) * KP + kb * 64 + sseg * 8];
            uint4 bv = *(const uint4*)&B[(size_t)(c0 + row) * KP + kb * 64 + sseg * 8];
            *(uint4*)&As[row * BKU + sseg * 8] = av;
            *(uint4*)&Bs[row * BKU + sseg * 8] = bv;
        }
        __syncthreads();
#pragma unroll
        for (int kk = 0; kk < 2; kk++) {
            short8 af[4], bf[4];
#pragma unroll
            for (int r = 0; r < 4; r++)
                af[r] = *(const short8*)&As[(wm * 64 + r * 16 + (lane & 15)) * BKU + kk * 32 + (lane >> 4) * 8];
#pragma unroll
            for (int c = 0; c < 4; c++)
                bf[c] = *(const short8*)&Bs[(wn * 64 + c * 16 + (lane & 15)) * BKU + kk * 32 + (lane >> 4) * 8];
#pragma unroll
            for (int r = 0; r < 4; r++)
#pragma unroll
                for (int c = 0; c < 4; c++)
                    acc[r][c] = __builtin_amdgcn_mfma_f32_16x16x32_bf16(af[r], bf[c], acc[r][c], 0, 0, 0);
        }
    }

    // epilogue: D layout col = lane&15, row = (lane>>4)*4 + reg  [m89-verified]
    const int mq = (lane >> 4) * 4;
    const int nn = lane & 15;
#pragma unroll
    for (int r = 0; r < 4; r++) {
#pragma unroll
        for (int c = 0; c < 4; c++) {
            int cg = c0 + wn * 64 + c * 16 + nn;       // global column (bl*64+d)
            float bv = bias[cg & 63];
            int b_ = cg >> 11, rem = cg & 2047;
            float* op = out + (size_t)b_ * 4096000 + rem;
#pragma unroll
            for (int rg = 0; rg < 4; rg++) {
                int i = i0 + wm * 64 + r * 16 + mq + rg;
                if (i < NB) op[(size_t)i * 2048] = acc[r][c][rg] + bv;
            }
        }
    }
}

// ---------------------------------------------------------------------------
extern "C" void kernel_launch(void* const* d_in, const int* in_sizes, int n_in,
                              void* d_out, int out_size, void* d_ws, size_t ws_size,
                              hipStream_t stream)
{
    const float* x           = (const float*)d_in[0];
    const float* e1          = (const float*)d_in[1];
    const float* e2          = (const float*)d_in[2];
    const float* temperature = (const float*)d_in[3];
    const float* ew1         = (const float*)d_in[4];
    const float* eb1         = (const float*)d_in[5];
    const float* ew2         = (const float*)d_in[6];
    const float* eb2         = (const float*)d_in[7];
    const float* weight      = (const float*)d_in[8];
    const float* bias        = (const float*)d_in[9];

    float* out  = (float*)d_out;            // (B,N,L,DOUT) = 16,384,000 floats
    float* fadj = out + 16384000;           // (N,N)        =  4,000,000 floats

    // workspace: ST (8192xKP bf16) | S_b (2000x8192 bf16) | faT_b (2048xKP bf16) | topk
    ushort* ST       = (ushort*)d_ws;                 // 16,777,216 us = 33.55 MB
    ushort* S_b      = ST + (size_t)8192 * KP;        // 16,384,000 us = 32.77 MB
    ushort* faT_b    = S_b + (size_t)NB * 8192;       //  4,194,304 us =  8.39 MB
    int*    topk_idx = (int*)(faT_b + (size_t)KP * KP); // 160,000
    float*  topk_val = (float*)(topk_idx + 160000);     // 160,000
    // total ~76.0 MB (<= proven ws usage of round 1)

    hipMemsetAsync(faT_b, 0, (size_t)KP * KP * sizeof(ushort), stream);

    k_scores_topk<<<dim3(NB, HH), 256, 0, stream>>>(e1, e2, temperature,
                                                    topk_idx, topk_val);
    k_final_adj<<<NB, 256, 0, stream>>>(topk_idx, topk_val, ew1, eb1, ew2, eb2,
                                        fadj, faT_b);
    k_support<<<NB, 256, 0, stream>>>(x, weight, S_b);
    k_transpose<<<dim3(32, 128), 256, 0, stream>>>(S_b, ST);
    k_gemm<<<dim3(16, 64), 256, 0, stream>>>(faT_b, ST, bias, out);
}

// Round 3
// 466.423 us; speedup vs baseline: 2.8900x; 1.6986x over previous
//
#include <hip/hip_runtime.h>

#define NB   2000   // N
#define HH   4      // heads
#define KK   20     // topk
#define KP   2048   // padded K (j) dim for GEMM
#define GA   4      // rows per k_scores block
#define EPSF 1e-8f

typedef unsigned short ushort;
typedef unsigned long long ull;
using short8   = __attribute__((ext_vector_type(8))) short;
using floatx4  = __attribute__((ext_vector_type(4))) float;
using ushortx4 = __attribute__((ext_vector_type(4))) unsigned short;
using ushortx8 = __attribute__((ext_vector_type(8))) unsigned short;

__device__ inline ushort f2bf(float f) {
    unsigned u = __builtin_bit_cast(unsigned, f);
    u += 0x7fffu + ((u >> 16) & 1u);   // round-to-nearest-even
    return (ushort)(u >> 16);
}

__device__ inline ull shfl_xor_u64(ull x, int off) {
    unsigned lo = (unsigned)x, hi = (unsigned)(x >> 32);
    lo = (unsigned)__shfl_xor((int)lo, off, 64);
    hi = (unsigned)__shfl_xor((int)hi, off, 64);
    return ((ull)hi << 32) | lo;
}

#define COMP(v,i) ((i)==0?(v).x:(i)==1?(v).y:(i)==2?(v).z:(v).w)

// ---------------------------------------------------------------------------
// Kernel A: scores + (Z-free) softmax for GA=4 rows of one head per block.
// Wave w owns columns m = w*512 + lane*8 + k (two float4 e2 loads per d-iter,
// each reused across 4 rows -> 4x less e2 traffic). Stores unnormalized
// pv = exp(relu(s)/T - rowmax) to adjw[h*N+n][0..1999] (fp32).
// Z-normalization is provably cancelled by the later selected-sum renorm.
// ---------------------------------------------------------------------------
__global__ __launch_bounds__(256) void k_scores(
    const float* __restrict__ e1, const float* __restrict__ e2,
    const float* __restrict__ temperature, float* __restrict__ adjw)
{
    const int h  = blockIdx.y;
    const int n0 = blockIdx.x * GA;
    const int t  = threadIdx.x;
    const int w  = t >> 6, lane = t & 63;

    __shared__ float e1s[GA][64];
    __shared__ float red[GA][4];

    { int r = t >> 6, d = t & 63;
      e1s[r][d] = e1[(size_t)(h * NB + n0 + r) * 64 + d]; }
    __syncthreads();

    const float rtemp = 1.f / temperature[h];
    const float* __restrict__ e2h = e2 + (size_t)h * 64 * NB;

    const int  mbase = w * 512 + lane * 8;
    const bool valid = (mbase < NB);            // all-8-or-none (NB%8==0)
    const int  mload = valid ? mbase : (NB - 8);

    float acc[GA][8];
#pragma unroll
    for (int r = 0; r < GA; r++)
#pragma unroll
        for (int k = 0; k < 8; k++) acc[r][k] = 0.f;

    for (int d4 = 0; d4 < 64; d4 += 4) {
        float4 ev0 = *(const float4*)&e1s[0][d4];
        float4 ev1 = *(const float4*)&e1s[1][d4];
        float4 ev2 = *(const float4*)&e1s[2][d4];
        float4 ev3 = *(const float4*)&e1s[3][d4];
#pragma unroll
        for (int dd = 0; dd < 4; dd++) {
            const float* __restrict__ row = e2h + (size_t)(d4 + dd) * NB + mload;
            float4 a = *(const float4*)row;
            float4 b = *(const float4*)(row + 4);
            float f0 = COMP(ev0, dd), f1 = COMP(ev1, dd);
            float f2 = COMP(ev2, dd), f3 = COMP(ev3, dd);
            acc[0][0] += f0*a.x; acc[0][1] += f0*a.y; acc[0][2] += f0*a.z; acc[0][3] += f0*a.w;
            acc[0][4] += f0*b.x; acc[0][5] += f0*b.y; acc[0][6] += f0*b.z; acc[0][7] += f0*b.w;
            acc[1][0] += f1*a.x; acc[1][1] += f1*a.y; acc[1][2] += f1*a.z; acc[1][3] += f1*a.w;
            acc[1][4] += f1*b.x; acc[1][5] += f1*b.y; acc[1][6] += f1*b.z; acc[1][7] += f1*b.w;
            acc[2][0] += f2*a.x; acc[2][1] += f2*a.y; acc[2][2] += f2*a.z; acc[2][3] += f2*a.w;
            acc[2][4] += f2*b.x; acc[2][5] += f2*b.y; acc[2][6] += f2*b.z; acc[2][7] += f2*b.w;
            acc[3][0] += f3*a.x; acc[3][1] += f3*a.y; acc[3][2] += f3*a.z; acc[3][3] += f3*a.w;
            acc[3][4] += f3*b.x; acc[3][5] += f3*b.y; acc[3][6] += f3*b.z; acc[3][7] += f3*b.w;
        }
    }

    // tv = relu(acc)*rtemp; per-row wave max -> cross-wave max via LDS
#pragma unroll
    for (int r = 0; r < GA; r++) {
        float tvm = 0.f;
#pragma unroll
        for (int k = 0; k < 8; k++) {
            float v = fmaxf(acc[r][k], 0.f) * rtemp;
            acc[r][k] = v;
            tvm = fmaxf(tvm, v);
        }
        if (!valid) tvm = 0.f;                  // relu >= 0, 0 is neutral
        for (int off = 32; off; off >>= 1) tvm = fmaxf(tvm, __shfl_xor(tvm, off, 64));
        if (lane == 0) red[r][w] = tvm;
    }
    __syncthreads();

    if (valid) {
#pragma unroll
        for (int r = 0; r < GA; r++) {
            float mx = fmaxf(fmaxf(red[r][0], red[r][1]), fmaxf(red[r][2], red[r][3]));
            float4 o0, o1;
            o0.x = __expf(acc[r][0] - mx); o0.y = __expf(acc[r][1] - mx);
            o0.z = __expf(acc[r][2] - mx); o0.w = __expf(acc[r][3] - mx);
            o1.x = __expf(acc[r][4] - mx); o1.y = __expf(acc[r][5] - mx);
            o1.z = __expf(acc[r][6] - mx); o1.w = __expf(acc[r][7] - mx);
            float* dst = adjw + (size_t)(h * NB + n0 + r) * 2000 + mbase;
            *(float4*)dst       = o0;
            *(float4*)(dst + 4) = o1;
        }
    }
}

// ---------------------------------------------------------------------------
// Kernel B: per (n,h) row top-20. Each wave: top-20 of its 512 elements,
// held in registers as packed u64 keys (fbits(v)<<32 | ~m) -> unsigned max
// == (value desc, index asc) == jax.lax.top_k tiebreak. Barrier-free rounds;
// then serial 4-list merge on thread 0; renorm by selected-sum + eps.
// ---------------------------------------------------------------------------
__global__ __launch_bounds__(256) void k_topk(
    const float* __restrict__ adjw,
    int* __restrict__ topk_idx, float* __restrict__ topk_val)
{
    const int n = blockIdx.x, h = blockIdx.y;
    const int t = threadIdx.x, w = t >> 6, lane = t & 63;

    __shared__ ull   lists[4][KK + 1];
    __shared__ float sel_v[KK];
    __shared__ int   sel_i[KK];
    __shared__ float ssum_sh;

    const int mbase = w * 512 + lane * 8;
    const float* __restrict__ rowp = adjw + (size_t)(h * NB + n) * 2000;

    ull key[8];
    if (mbase < NB) {
        float4 a = *(const float4*)(rowp + mbase);
        float4 b = *(const float4*)(rowp + mbase + 4);
        float v[8] = {a.x, a.y, a.z, a.w, b.x, b.y, b.z, b.w};
#pragma unroll
        for (int k = 0; k < 8; k++)
            key[k] = ((ull)__float_as_uint(v[k]) << 32) | (unsigned)~(mbase + k);
    } else {
#pragma unroll
        for (int k = 0; k < 8; k++) key[k] = (unsigned)~(mbase + k);
    }

    for (int r = 0; r < KK; r++) {
        ull a01 = key[0] > key[1] ? key[0] : key[1];
        ull a23 = key[2] > key[3] ? key[2] : key[3];
        ull a45 = key[4] > key[5] ? key[4] : key[5];
        ull a67 = key[6] > key[7] ? key[6] : key[7];
        ull a03 = a01 > a23 ? a01 : a23;
        ull a47 = a45 > a67 ? a45 : a67;
        ull best = a03 > a47 ? a03 : a47;
        for (int off = 32; off; off >>= 1) {
            ull o = shfl_xor_u64(best, off);
            if (o > best) best = o;
        }
        if (lane == 0) lists[w][r] = best;
#pragma unroll
        for (int k = 0; k < 8; k++)
            if (key[k] == best) key[k] = 0ULL;   // keys unique (index embedded)
    }
    if (lane == 0) lists[w][KK] = 0ULL;          // merge sentinel
    __syncthreads();

    if (t == 0) {
        int p0 = 0, p1 = 0, p2 = 0, p3 = 0;
        ull h0 = lists[0][0], h1 = lists[1][0], h2 = lists[2][0], h3 = lists[3][0];
        float ssum = 0.f;
        for (int r = 0; r < KK; r++) {
            ull a_ = h0 >= h1 ? h0 : h1; int wa = h0 >= h1 ? 0 : 1;
            ull b_ = h2 >= h3 ? h2 : h3; int wb = h2 >= h3 ? 2 : 3;
            ull bk = a_ >= b_ ? a_ : b_; int bw = a_ >= b_ ? wa : wb;
            float pv = __uint_as_float((unsigned)(bk >> 32));
            sel_v[r] = pv;
            sel_i[r] = (int)~(unsigned)bk;
            ssum += pv;
            if      (bw == 0) h0 = lists[0][++p0];
            else if (bw == 1) h1 = lists[1][++p1];
            else if (bw == 2) h2 = lists[2][++p2];
            else              h3 = lists[3][++p3];
        }
        ssum_sh = ssum;
    }
    __syncthreads();
    if (t < KK) {
        int o = (h * NB + n) * KK + t;
        topk_idx[o] = sel_i[t];
        topk_val[o] = sel_v[t] / (ssum_sh + EPSF);
    }
}

// ---------------------------------------------------------------------------
// Kernel 2: final_adj row i; writes dense fp32 fadj (output) and scatters
// nonzeros into bf16 A-matrix faT_b[m=i][k=j] (pre-zeroed, K padded to 2048).
// ---------------------------------------------------------------------------
__global__ __launch_bounds__(256) void k_final_adj(
    const int* __restrict__ topk_idx, const float* __restrict__ topk_val,
    const float* __restrict__ ew1, const float* __restrict__ eb1,
    const float* __restrict__ ew2, const float* __restrict__ eb2,
    float* __restrict__ fadj_out, ushort* __restrict__ faT_b)
{
    const int i = blockIdx.x;
    const int t = threadIdx.x;

    __shared__ float rows[HH][NB];
    __shared__ float w1[32];
    __shared__ float b1[8];
    __shared__ float w2[8];
    __shared__ float b2v;

    for (int k = t; k < HH * NB; k += 256) ((float*)rows)[k] = 0.f;
    if (t < 32) w1[t] = ew1[t];
    if (t < 8)  { b1[t] = eb1[t]; w2[t] = ew2[t]; }
    if (t == 0) b2v = eb2[0];
    __syncthreads();

    if (t < HH * KK) {
        int h = t / KK, r = t % KK;
        int o = (h * NB + i) * KK + r;
        rows[h][topk_idx[o]] = topk_val[o];
    }
    __syncthreads();

#pragma unroll
    for (int k = 0; k < 8; k++) {
        int j = k * 256 + t;
        if (j < NB) {
            float f0 = rows[0][j], f1 = rows[1][j], f2 = rows[2][j], f3 = rows[3][j];
            float mean = (f0 + f1 + f2 + f3) * 0.25f;
            float outv = 0.f;
            if (mean > 0.f) {
                float ewv = b2v;
#pragma unroll
                for (int c = 0; c < 8; c++) {
                    float hid = f0 * w1[c] + f1 * w1[8 + c] + f2 * w1[16 + c] + f3 * w1[24 + c] + b1[c];
                    hid = fmaxf(hid, 0.f);
                    ewv += hid * w2[c];
                }
                float sig = 1.f / (1.f + expf(-ewv));
                outv = sig * mean;
                faT_b[(size_t)j * KP + i] = f2bf(outv);  // A[m=i][k=j] scatter
            }
            fadj_out[(size_t)i * NB + j] = outv;
        }
    }
}

// ---------------------------------------------------------------------------
// Kernel 3: support S_b[j][bl*64+d] (bf16, j-major) = x[b,j,l,:] @ W
// ---------------------------------------------------------------------------
__global__ __launch_bounds__(256) void k_support(
    const float* __restrict__ x, const float* __restrict__ w,
    ushort* __restrict__ S_b)
{
    const int j = blockIdx.x;
    const int t = threadIdx.x;

    __shared__ float xs[128 * 65];
    __shared__ float ws[64 * 64];

    for (int k = t; k < 4096; k += 256) ws[k] = w[k];
    for (int idx = t; idx < 8192; idx += 256) {
        int b_ = idx >> 11, rem = idx & 2047;
        int bl = (b_ << 5) + (rem >> 6), dd = rem & 63;
        xs[bl * 65 + dd] = x[(size_t)b_ * 4096000 + (size_t)j * 2048 + rem];
    }
    __syncthreads();

    const int dq = t & 15;
    const int g  = t >> 4;
    float acc[8][4];
#pragma unroll
    for (int r = 0; r < 8; r++)
#pragma unroll
        for (int c = 0; c < 4; c++) acc[r][c] = 0.f;

    for (int dd = 0; dd < 64; dd++) {
        float4 w4 = *(const float4*)&ws[dd * 64 + dq * 4];
#pragma unroll
        for (int r = 0; r < 8; r++) {
            float xv = xs[(g * 8 + r) * 65 + dd];
            acc[r][0] += xv * w4.x;
            acc[r][1] += xv * w4.y;
            acc[r][2] += xv * w4.z;
            acc[r][3] += xv * w4.w;
        }
    }

#pragma unroll
    for (int r = 0; r < 8; r++) {
        int bl = g * 8 + r;
        ushortx4 v;
        v.x = f2bf(acc[r][0]); v.y = f2bf(acc[r][1]);
        v.z = f2bf(acc[r][2]); v.w = f2bf(acc[r][3]);
        *(ushortx4*)&S_b[(size_t)j * 8192 + bl * 64 + dq * 4] = v;
    }
}

// ---------------------------------------------------------------------------
// Kernel 4: transpose S_b[j][c] (2000x8192 bf16) -> ST[c][j] (8192xKP bf16),
// zero-padding j in [2000,2048). 64x64 tiles via LDS.
// ---------------------------------------------------------------------------
__global__ __launch_bounds__(256) void k_transpose(
    const ushort* __restrict__ S_b, ushort* __restrict__ ST)
{
    const int jt = blockIdx.x;   // 0..31
    const int ct = blockIdx.y;   // 0..127
    const int t  = threadIdx.x;

    __shared__ ushort tile[64 * 65];

#pragma unroll
    for (int p = 0; p < 4; p++) {
        int q = p * 256 + t;
        int row = q >> 4, seg = q & 15;
        int j = jt * 64 + row;
        ushort v0 = 0, v1 = 0, v2 = 0, v3 = 0;
        if (j < NB) {
            const ushort* src = &S_b[(size_t)j * 8192 + ct * 64 + seg * 4];
            v0 = src[0]; v1 = src[1]; v2 = src[2]; v3 = src[3];
        }
        ushort* dst = &tile[row * 65 + seg * 4];
        dst[0] = v0; dst[1] = v1; dst[2] = v2; dst[3] = v3;
    }
    __syncthreads();

#pragma unroll
    for (int p = 0; p < 2; p++) {
        int q = p * 256 + t;
        int rc = q >> 3, s = q & 7;
        ushortx8 o;
#pragma unroll
        for (int k = 0; k < 8; k++) o[k] = tile[(s * 8 + k) * 65 + rc];
        *(ushortx8*)&ST[(size_t)(ct * 64 + rc) * KP + jt * 64 + s * 8] = o;
    }
}

// ---------------------------------------------------------------------------
// Kernel 5: MFMA bf16 GEMM: out[i][c] = sum_j A[i][j] * B[c][j]
// ---------------------------------------------------------------------------
#define BKU 72
__global__ __launch_bounds__(256) void k_gemm(
    const ushort* __restrict__ A, const ushort* __restrict__ B,
    const float* __restrict__ bias, float* __restrict__ out)
{
    __shared__ ushort As[128 * BKU];
    __shared__ ushort Bs[128 * BKU];

    const int t    = threadIdx.x;
    const int lane = t & 63, wave = t >> 6;
    const int wm   = wave & 1, wn = wave >> 1;
    const int i0   = blockIdx.x * 128;
    const int c0   = blockIdx.y * 128;
    const int srow = t >> 3, sseg = t & 7;

    floatx4 acc[4][4];
#pragma unroll
    for (int r = 0; r < 4; r++)
#pragma unroll
        for (int c = 0; c < 4; c++) acc[r][c] = (floatx4)(0.f);

    for (int kb = 0; kb < 32; kb++) {
        __syncthreads();
#pragma unroll
        for (int p = 0; p < 4; p++) {
            int row = p * 32 + srow;
            uint4 av = *(const uint4*)&A[(size_t)(i0 + row) * KP + kb * 64 + sseg * 8];
            uint4 bv = *(const uint4*)&B[(size_t)(c0 + row) * KP + kb * 64 + sseg * 8];
            *(uint4*)&As[row * BKU + sseg * 8] = av;
            *(uint4*)&Bs[row * BKU + sseg * 8] = bv;
        }
        __syncthreads();
#pragma unroll
        for (int kk = 0; kk < 2; kk++) {
            short8 af[4], bf[4];
#pragma unroll
            for (int r = 0; r < 4; r++)
                af[r] = *(const short8*)&As[(wm * 64 + r * 16 + (lane & 15)) * BKU + kk * 32 + (lane >> 4) * 8];
#pragma unroll
            for (int c = 0; c < 4; c++)
                bf[c] = *(const short8*)&Bs[(wn * 64 + c * 16 + (lane & 15)) * BKU + kk * 32 + (lane >> 4) * 8];
#pragma unroll
            for (int r = 0; r < 4; r++)
#pragma unroll
                for (int c = 0; c < 4; c++)
                    acc[r][c] = __builtin_amdgcn_mfma_f32_16x16x32_bf16(af[r], bf[c], acc[r][c], 0, 0, 0);
        }
    }

    const int mq = (lane >> 4) * 4;
    const int nn = lane & 15;
#pragma unroll
    for (int r = 0; r < 4; r++) {
#pragma unroll
        for (int c = 0; c < 4; c++) {
            int cg = c0 + wn * 64 + c * 16 + nn;
            float bv = bias[cg & 63];
            int b_ = cg >> 11, rem = cg & 2047;
            float* op = out + (size_t)b_ * 4096000 + rem;
#pragma unroll
            for (int rg = 0; rg < 4; rg++) {
                int i = i0 + wm * 64 + r * 16 + mq + rg;
                if (i < NB) op[(size_t)i * 2048] = acc[r][c][rg] + bv;
            }
        }
    }
}

// ---------------------------------------------------------------------------
extern "C" void kernel_launch(void* const* d_in, const int* in_sizes, int n_in,
                              void* d_out, int out_size, void* d_ws, size_t ws_size,
                              hipStream_t stream)
{
    const float* x           = (const float*)d_in[0];
    const float* e1          = (const float*)d_in[1];
    const float* e2          = (const float*)d_in[2];
    const float* temperature = (const float*)d_in[3];
    const float* ew1         = (const float*)d_in[4];
    const float* eb1         = (const float*)d_in[5];
    const float* ew2         = (const float*)d_in[6];
    const float* eb2         = (const float*)d_in[7];
    const float* weight      = (const float*)d_in[8];
    const float* bias        = (const float*)d_in[9];

    float* out  = (float*)d_out;            // (B,N,L,DOUT) = 16,384,000 floats
    float* fadj = out + 16384000;           // (N,N)        =  4,000,000 floats

    // workspace (lifetimes disjoint -> aliasing):
    //   region0 [0 .. 66,322,432 B):
    //     adjw (fp32 8000x2000 = 64.0 MB)  live: k_scores -> k_topk
    //     ST   (bf16 8192xKP  = 33.55 MB)  live: k_transpose -> k_gemm
    //     S_b  (bf16 2000x8192 = 32.77 MB) live: k_support -> k_transpose
    //   region1: faT_b (bf16 KPxKP = 8.39 MB), topk arrays (1.28 MB)
    float*  adjw  = (float*)d_ws;
    ushort* ST    = (ushort*)d_ws;
    ushort* S_b   = (ushort*)d_ws + (size_t)8192 * KP;
    ushort* faT_b = (ushort*)d_ws + 33161216u;            // byte 66,322,432
    int*    topk_idx = (int*)(faT_b + (size_t)KP * KP);   // byte 74,711,040
    float*  topk_val = (float*)(topk_idx + 160000);
    // total ~76.0 MB

    hipMemsetAsync(faT_b, 0, (size_t)KP * KP * sizeof(ushort), stream);

    k_scores<<<dim3(NB / GA, HH), 256, 0, stream>>>(e1, e2, temperature, adjw);
    k_topk<<<dim3(NB, HH), 256, 0, stream>>>(adjw, topk_idx, topk_val);
    k_final_adj<<<NB, 256, 0, stream>>>(topk_idx, topk_val, ew1, eb1, ew2, eb2,
                                        fadj, faT_b);
    k_support<<<NB, 256, 0, stream>>>(x, weight, S_b);
    k_transpose<<<dim3(32, 128), 256, 0, stream>>>(S_b, ST);
    k_gemm<<<dim3(16, 64), 256, 0, stream>>>(faT_b, ST, bias, out);
}

// Round 4
// 423.412 us; speedup vs baseline: 3.1836x; 1.1016x over previous
//
#include <hip/hip_runtime.h>

#define NB   2000   // N
#define HH   4      // heads
#define KK   20     // topk
#define KP   2048   // padded K (j) dim for GEMM
#define GA   4      // rows per k_scores_topk block
#define EPSF 1e-8f

typedef unsigned short ushort;
typedef unsigned long long ull;
using short8   = __attribute__((ext_vector_type(8))) short;
using floatx4  = __attribute__((ext_vector_type(4))) float;
using ushortx4 = __attribute__((ext_vector_type(4))) unsigned short;
using ushortx8 = __attribute__((ext_vector_type(8))) unsigned short;

__device__ inline ushort f2bf(float f) {
    unsigned u = __builtin_bit_cast(unsigned, f);
    u += 0x7fffu + ((u >> 16) & 1u);   // round-to-nearest-even
    return (ushort)(u >> 16);
}

__device__ __forceinline__ void gload_lds16(const ushort* g, ushort* l) {
    __builtin_amdgcn_global_load_lds(
        (const __attribute__((address_space(1))) void*)g,
        (__attribute__((address_space(3))) void*)l, 16, 0, 0);
}

#define COMP(v,i) ((i)==0?(v).x:(i)==1?(v).y:(i)==2?(v).z:(v).w)

// ---------------------------------------------------------------------------
// Kernel 1 (fused): scores + top-20 in score domain for GA=4 rows of one head.
// Wave w owns cols mbase = w*512 + lane*8 (2x float4 e2 loads reused across
// 4 rows). Selection: per-round f32 butterfly max + ballot (lowest lane =
// lowest index), winner-lane clear+recompute. Waves' top-20 lists merged as
// packed u64 (valbits<<32 | ~idx) => exact jax.lax.top_k tiebreak. exp()
// applied to the 20 winners only; renorm by selected-sum (Z cancels).
// ---------------------------------------------------------------------------
__global__ __launch_bounds__(256) void k_scores_topk(
    const float* __restrict__ e1, const float* __restrict__ e2,
    const float* __restrict__ temperature,
    int* __restrict__ topk_idx, float* __restrict__ topk_val)
{
    const int h  = blockIdx.y;
    const int n0 = blockIdx.x * GA;
    const int t  = threadIdx.x;
    const int w  = t >> 6, lane = t & 63;

    __shared__ float e1s[GA][64];
    __shared__ float red[GA][4];
    __shared__ ull   lists[4][GA][KK + 1];
    __shared__ float selpv[GA][KK];
    __shared__ int   seli[GA][KK];
    __shared__ float ssum[GA];

    e1s[t >> 6][t & 63] = e1[(size_t)(h * NB + n0 + (t >> 6)) * 64 + (t & 63)];
    __syncthreads();

    const float rtemp = 1.f / temperature[h];
    const float* __restrict__ e2h = e2 + (size_t)h * 64 * NB;

    const int  mbase = w * 512 + lane * 8;
    const bool valid = (mbase < NB);            // all-8-or-none (NB%8==0)
    const int  mload = valid ? mbase : (NB - 8);

    float acc[GA][8];
#pragma unroll
    for (int r = 0; r < GA; r++)
#pragma unroll
        for (int k = 0; k < 8; k++) acc[r][k] = 0.f;

    for (int d4 = 0; d4 < 64; d4 += 4) {
        float4 ev0 = *(const float4*)&e1s[0][d4];
        float4 ev1 = *(const float4*)&e1s[1][d4];
        float4 ev2 = *(const float4*)&e1s[2][d4];
        float4 ev3 = *(const float4*)&e1s[3][d4];
#pragma unroll
        for (int dd = 0; dd < 4; dd++) {
            const float* __restrict__ row = e2h + (size_t)(d4 + dd) * NB + mload;
            float4 a = *(const float4*)row;
            float4 b = *(const float4*)(row + 4);
            float f0 = COMP(ev0, dd), f1 = COMP(ev1, dd);
            float f2 = COMP(ev2, dd), f3 = COMP(ev3, dd);
            acc[0][0] += f0*a.x; acc[0][1] += f0*a.y; acc[0][2] += f0*a.z; acc[0][3] += f0*a.w;
            acc[0][4] += f0*b.x; acc[0][5] += f0*b.y; acc[0][6] += f0*b.z; acc[0][7] += f0*b.w;
            acc[1][0] += f1*a.x; acc[1][1] += f1*a.y; acc[1][2] += f1*a.z; acc[1][3] += f1*a.w;
            acc[1][4] += f1*b.x; acc[1][5] += f1*b.y; acc[1][6] += f1*b.z; acc[1][7] += f1*b.w;
            acc[2][0] += f2*a.x; acc[2][1] += f2*a.y; acc[2][2] += f2*a.z; acc[2][3] += f2*a.w;
            acc[2][4] += f2*b.x; acc[2][5] += f2*b.y; acc[2][6] += f2*b.z; acc[2][7] += f2*b.w;
            acc[3][0] += f3*a.x; acc[3][1] += f3*a.y; acc[3][2] += f3*a.z; acc[3][3] += f3*a.w;
            acc[3][4] += f3*b.x; acc[3][5] += f3*b.y; acc[3][6] += f3*b.z; acc[3][7] += f3*b.w;
        }
    }

    // tv = relu(acc)*rtemp ; invalid tail lanes -> -1 sentinel (< any valid tv)
#pragma unroll
    for (int r = 0; r < GA; r++) {
        float tvm = -1.f;
#pragma unroll
        for (int k = 0; k < 8; k++) {
            float v = valid ? fmaxf(acc[r][k], 0.f) * rtemp : -1.f;
            acc[r][k] = v;
            tvm = fmaxf(tvm, v);
        }
        for (int off = 32; off; off >>= 1) tvm = fmaxf(tvm, __shfl_xor(tvm, off, 64));
        if (lane == 0) red[r][w] = tvm;   // slice max (for exp shift)
    }

    // selection: 20 rounds per row, all 4 waves on their own 512-col slices
    for (int r = 0; r < GA; r++) {
        float lm = acc[r][0];
        int   ak = 0;
#pragma unroll
        for (int k = 1; k < 8; k++)
            if (acc[r][k] > lm) { lm = acc[r][k]; ak = k; }   // strict > keeps lowest k

        for (int round = 0; round < KK; round++) {
            float M = lm;
            for (int off = 32; off; off >>= 1) M = fmaxf(M, __shfl_xor(M, off, 64));
            ull ball = __ballot(lm == M);
            int wl   = __ffsll(ball) - 1;       // lowest lane = lowest global idx
            if (lane == wl) {
                int gidx = mbase + ak;
                lists[w][r][round] =
                    ((ull)__float_as_uint(M) << 32) | (unsigned)~gidx;
#pragma unroll
                for (int k = 0; k < 8; k++) if (k == ak) acc[r][k] = -2.f;
                lm = acc[r][0]; ak = 0;
#pragma unroll
                for (int k = 1; k < 8; k++)
                    if (acc[r][k] > lm) { lm = acc[r][k]; ak = k; }
            }
        }
        if (lane == 0) lists[w][r][KK] = 0ULL;  // merge sentinel
    }
    __syncthreads();

    // merge 4 sorted lists per row; lanes 0..3 of wave 0 handle one row each
    if (t < GA) {
        const int r = t;
        float mx = fmaxf(fmaxf(red[r][0], red[r][1]), fmaxf(red[r][2], red[r][3]));
        int p0 = 0, p1 = 0, p2 = 0, p3 = 0;
        ull h0 = lists[0][r][0], h1 = lists[1][r][0];
        ull h2 = lists[2][r][0], h3 = lists[3][r][0];
        float ss = 0.f;
        for (int q = 0; q < KK; q++) {
            ull a_ = h0 >= h1 ? h0 : h1; int wa = h0 >= h1 ? 0 : 1;
            ull b_ = h2 >= h3 ? h2 : h3; int wb = h2 >= h3 ? 2 : 3;
            ull bk = a_ >= b_ ? a_ : b_; int bw = a_ >= b_ ? wa : wb;
            float tvv = __uint_as_float((unsigned)(bk >> 32));
            float pv  = __expf(tvv - mx);
            selpv[r][q] = pv;
            seli[r][q]  = (int)~(unsigned)bk;
            ss += pv;
            if      (bw == 0) h0 = lists[0][r][++p0];
            else if (bw == 1) h1 = lists[1][r][++p1];
            else if (bw == 2) h2 = lists[2][r][++p2];
            else              h3 = lists[3][r][++p3];
        }
        ssum[r] = ss;
    }
    __syncthreads();

    if (t < GA * KK) {
        int r = t / KK, q = t % KK;
        int o = (h * NB + n0 + r) * KK + q;
        topk_idx[o] = seli[r][q];
        topk_val[o] = selpv[r][q] / (ssum[r] + EPSF);
    }
}

// ---------------------------------------------------------------------------
// Kernel 2: final_adj row i; writes dense fp32 fadj (output) and scatters
// nonzeros into bf16 A-matrix faT_b[m=i][k=j] (pre-zeroed, K padded to 2048).
// ---------------------------------------------------------------------------
__global__ __launch_bounds__(256) void k_final_adj(
    const int* __restrict__ topk_idx, const float* __restrict__ topk_val,
    const float* __restrict__ ew1, const float* __restrict__ eb1,
    const float* __restrict__ ew2, const float* __restrict__ eb2,
    float* __restrict__ fadj_out, ushort* __restrict__ faT_b)
{
    const int i = blockIdx.x;
    const int t = threadIdx.x;

    __shared__ float rows[HH][NB];
    __shared__ float w1[32];
    __shared__ float b1[8];
    __shared__ float w2[8];
    __shared__ float b2v;

    for (int k = t; k < HH * NB; k += 256) ((float*)rows)[k] = 0.f;
    if (t < 32) w1[t] = ew1[t];
    if (t < 8)  { b1[t] = eb1[t]; w2[t] = ew2[t]; }
    if (t == 0) b2v = eb2[0];
    __syncthreads();

    if (t < HH * KK) {
        int h = t / KK, r = t % KK;
        int o = (h * NB + i) * KK + r;
        rows[h][topk_idx[o]] = topk_val[o];
    }
    __syncthreads();

#pragma unroll
    for (int k = 0; k < 8; k++) {
        int j = k * 256 + t;
        if (j < NB) {
            float f0 = rows[0][j], f1 = rows[1][j], f2 = rows[2][j], f3 = rows[3][j];
            float mean = (f0 + f1 + f2 + f3) * 0.25f;
            float outv = 0.f;
            if (mean > 0.f) {
                float ewv = b2v;
#pragma unroll
                for (int c = 0; c < 8; c++) {
                    float hid = f0 * w1[c] + f1 * w1[8 + c] + f2 * w1[16 + c] + f3 * w1[24 + c] + b1[c];
                    hid = fmaxf(hid, 0.f);
                    ewv += hid * w2[c];
                }
                float sig = 1.f / (1.f + expf(-ewv));
                outv = sig * mean;
                faT_b[(size_t)j * KP + i] = f2bf(outv);  // A[m=i][k=j] scatter
            }
            fadj_out[(size_t)i * NB + j] = outv;
        }
    }
}

// ---------------------------------------------------------------------------
// Kernel 3: support S_b[j][bl*64+d] (bf16, j-major) = x[b,j,l,:] @ W
// ---------------------------------------------------------------------------
__global__ __launch_bounds__(256) void k_support(
    const float* __restrict__ x, const float* __restrict__ w,
    ushort* __restrict__ S_b)
{
    const int j = blockIdx.x;
    const int t = threadIdx.x;

    __shared__ float xs[128 * 65];
    __shared__ float ws[64 * 64];

    for (int k = t; k < 4096; k += 256) ws[k] = w[k];
    for (int idx = t; idx < 8192; idx += 256) {
        int b_ = idx >> 11, rem = idx & 2047;
        int bl = (b_ << 5) + (rem >> 6), dd = rem & 63;
        xs[bl * 65 + dd] = x[(size_t)b_ * 4096000 + (size_t)j * 2048 + rem];
    }
    __syncthreads();

    const int dq = t & 15;
    const int g  = t >> 4;
    float acc[8][4];
#pragma unroll
    for (int r = 0; r < 8; r++)
#pragma unroll
        for (int c = 0; c < 4; c++) acc[r][c] = 0.f;

    for (int dd = 0; dd < 64; dd++) {
        float4 w4 = *(const float4*)&ws[dd * 64 + dq * 4];
#pragma unroll
        for (int r = 0; r < 8; r++) {
            float xv = xs[(g * 8 + r) * 65 + dd];
            acc[r][0] += xv * w4.x;
            acc[r][1] += xv * w4.y;
            acc[r][2] += xv * w4.z;
            acc[r][3] += xv * w4.w;
        }
    }

#pragma unroll
    for (int r = 0; r < 8; r++) {
        int bl = g * 8 + r;
        ushortx4 v;
        v.x = f2bf(acc[r][0]); v.y = f2bf(acc[r][1]);
        v.z = f2bf(acc[r][2]); v.w = f2bf(acc[r][3]);
        *(ushortx4*)&S_b[(size_t)j * 8192 + bl * 64 + dq * 4] = v;
    }
}

// ---------------------------------------------------------------------------
// Kernel 4: transpose S_b[j][c] (2000x8192 bf16) -> ST[c][j] (8192xKP bf16),
// zero-padding j in [2000,2048). 64x64 tiles via LDS.
// ---------------------------------------------------------------------------
__global__ __launch_bounds__(256) void k_transpose(
    const ushort* __restrict__ S_b, ushort* __restrict__ ST)
{
    const int jt = blockIdx.x;   // 0..31
    const int ct = blockIdx.y;   // 0..127
    const int t  = threadIdx.x;

    __shared__ ushort tile[64 * 65];

#pragma unroll
    for (int p = 0; p < 4; p++) {
        int q = p * 256 + t;
        int row = q >> 4, seg = q & 15;
        int j = jt * 64 + row;
        ushort v0 = 0, v1 = 0, v2 = 0, v3 = 0;
        if (j < NB) {
            const ushort* src = &S_b[(size_t)j * 8192 + ct * 64 + seg * 4];
            v0 = src[0]; v1 = src[1]; v2 = src[2]; v3 = src[3];
        }
        ushort* dst = &tile[row * 65 + seg * 4];
        dst[0] = v0; dst[1] = v1; dst[2] = v2; dst[3] = v3;
    }
    __syncthreads();

#pragma unroll
    for (int p = 0; p < 2; p++) {
        int q = p * 256 + t;
        int rc = q >> 3, s = q & 7;
        ushortx8 o;
#pragma unroll
        for (int k = 0; k < 8; k++) o[k] = tile[(s * 8 + k) * 65 + rc];
        *(ushortx8*)&ST[(size_t)(ct * 64 + rc) * KP + jt * 64 + s * 8] = o;
    }
}

// ---------------------------------------------------------------------------
// Kernel 5: MFMA bf16 GEMM: out[i][c] = sum_j A[i][j] * B[c][j]
// global_load_lds width=16 staging (m97 ladder step). LDS image is lane-linear
// (wave-uniform base + lane*16), so the XOR swizzle g = dg ^ (row&7) is
// applied on the GLOBAL fetch side; frag ds_read_b128 then covers each bank
// once per 8-lane group (conflict-free, == stride-1 pattern permuted).
// ---------------------------------------------------------------------------
__global__ __launch_bounds__(256) void k_gemm(
    const ushort* __restrict__ A, const ushort* __restrict__ B,
    const float* __restrict__ bias, float* __restrict__ out)
{
    __shared__ ushort As[128 * 64];
    __shared__ ushort Bs[128 * 64];

    const int t    = threadIdx.x;
    const int lane = t & 63, wave = t >> 6;
    const int wm   = wave & 1, wn = wave >> 1;
    const int i0   = blockIdx.x * 128;
    const int c0   = blockIdx.y * 128;

    const int lr = lane >> 3;   // local row within 8-row chunk
    const int dg = lane & 7;    // LDS dest group (fixed by lane-linear DMA)

    floatx4 acc[4][4];
#pragma unroll
    for (int r = 0; r < 4; r++)
#pragma unroll
        for (int c = 0; c < 4; c++) acc[r][c] = (floatx4)(0.f);

    for (int kb = 0; kb < 32; kb++) {
        __syncthreads();
#pragma unroll
        for (int p = 0; p < 4; p++) {
            int rowb = p * 32 + wave * 8;           // chunk base row (mult of 8)
            int row  = rowb + lr;
            int g    = dg ^ lr;                     // row&7 == lr here
            const ushort* ga = &A[(size_t)(i0 + row) * KP + kb * 64 + g * 8];
            const ushort* gb = &B[(size_t)(c0 + row) * KP + kb * 64 + g * 8];
            gload_lds16(ga, &As[rowb * 64]);
            gload_lds16(gb, &Bs[rowb * 64]);
        }
        __syncthreads();   // compiler emits s_waitcnt vmcnt(0) before barrier

#pragma unroll
        for (int kk = 0; kk < 2; kk++) {
            short8 af[4], bf[4];
            const int gidx = kk * 4 + (lane >> 4);   // global k-group 0..7
            const int dsw  = gidx ^ (lane & 7);      // m&7 == lane&7 for frag rows
#pragma unroll
            for (int r = 0; r < 4; r++) {
                int m = wm * 64 + r * 16 + (lane & 15);
                af[r] = *(const short8*)&As[m * 64 + dsw * 8];
            }
#pragma unroll
            for (int c = 0; c < 4; c++) {
                int m = wn * 64 + c * 16 + (lane & 15);
                bf[c] = *(const short8*)&Bs[m * 64 + dsw * 8];
            }
#pragma unroll
            for (int r = 0; r < 4; r++)
#pragma unroll
                for (int c = 0; c < 4; c++)
                    acc[r][c] = __builtin_amdgcn_mfma_f32_16x16x32_bf16(af[r], bf[c], acc[r][c], 0, 0, 0);
        }
    }

    // epilogue: D layout col = lane&15, row = (lane>>4)*4 + reg  [m89-verified]
    const int mq = (lane >> 4) * 4;
    const int nn = lane & 15;
#pragma unroll
    for (int r = 0; r < 4; r++) {
#pragma unroll
        for (int c = 0; c < 4; c++) {
            int cg = c0 + wn * 64 + c * 16 + nn;
            float bv = bias[cg & 63];
            int b_ = cg >> 11, rem = cg & 2047;
            float* op = out + (size_t)b_ * 4096000 + rem;
#pragma unroll
            for (int rg = 0; rg < 4; rg++) {
                int i = i0 + wm * 64 + r * 16 + mq + rg;
                if (i < NB) op[(size_t)i * 2048] = acc[r][c][rg] + bv;
            }
        }
    }
}

// ---------------------------------------------------------------------------
extern "C" void kernel_launch(void* const* d_in, const int* in_sizes, int n_in,
                              void* d_out, int out_size, void* d_ws, size_t ws_size,
                              hipStream_t stream)
{
    const float* x           = (const float*)d_in[0];
    const float* e1          = (const float*)d_in[1];
    const float* e2          = (const float*)d_in[2];
    const float* temperature = (const float*)d_in[3];
    const float* ew1         = (const float*)d_in[4];
    const float* eb1         = (const float*)d_in[5];
    const float* ew2         = (const float*)d_in[6];
    const float* eb2         = (const float*)d_in[7];
    const float* weight      = (const float*)d_in[8];
    const float* bias        = (const float*)d_in[9];

    float* out  = (float*)d_out;            // (B,N,L,DOUT) = 16,384,000 floats
    float* fadj = out + 16384000;           // (N,N)        =  4,000,000 floats

    // workspace (no aliasing needed anymore; adjw eliminated):
    //   ST    bf16 8192xKP   = 33,554,432 B
    //   S_b   bf16 2000x8192 = 32,768,000 B
    //   faT_b bf16 KPxKP     =  8,388,608 B
    //   topk  idx+val        =  1,280,000 B      total ~76.0 MB
    ushort* ST       = (ushort*)d_ws;
    ushort* S_b      = ST + (size_t)8192 * KP;
    ushort* faT_b    = (ushort*)((char*)d_ws + 66322432u);
    int*    topk_idx = (int*)(faT_b + (size_t)KP * KP);
    float*  topk_val = (float*)(topk_idx + 160000);

    hipMemsetAsync(faT_b, 0, (size_t)KP * KP * sizeof(ushort), stream);

    k_scores_topk<<<dim3(NB / GA, HH), 256, 0, stream>>>(e1, e2, temperature,
                                                         topk_idx, topk_val);
    k_final_adj<<<NB, 256, 0, stream>>>(topk_idx, topk_val, ew1, eb1, ew2, eb2,
                                        fadj, faT_b);
    k_support<<<NB, 256, 0, stream>>>(x, weight, S_b);
    k_transpose<<<dim3(32, 128), 256, 0, stream>>>(S_b, ST);
    k_gemm<<<dim3(16, 64), 256, 0, stream>>>(faT_b, ST, bias, out);
}